// Round 1
// baseline (79987.274 us; speedup 1.0000x reference)
//
#include <hip/hip_runtime.h>
#include <hip/hip_bf16.h>

// Problem constants
#define T_  32
#define B_  32
#define C_  128
#define HS_ 512
#define RD_ 3
#define HW_ 7
#define S_  49            // HW*HW
#define IC_ 256           // 2C
#define OC_ 512           // 4C
#define CS_  (C_*S_)      // 6272
#define ICS_ (IC_*S_)     // 12544
#define OCS_ (OC_*S_)     // 25088

__device__ __forceinline__ float sigm_f(float v)      { return 1.0f / (1.0f + __expf(-v)); }
__device__ __forceinline__ float tanh_fast(float v)   { return 1.0f - 2.0f / (__expf(2.0f * v) + 1.0f); }

// ---------------------------------------------------------------------------
// Init: split hxs (B, 2C, 7,7) into h (B,C,49) and c (B,C,49)
// ---------------------------------------------------------------------------
__global__ __launch_bounds__(256) void k_init(const float* __restrict__ hxs,
                                              float* __restrict__ h,
                                              float* __restrict__ c) {
    int i = blockIdx.x * 256 + threadIdx.x;   // over B*C*S = 200704
    if (i >= B_ * CS_) return;
    int b = i / CS_;
    int r = i % CS_;
    h[i] = hxs[b * ICS_ + r];
    c[i] = hxs[b * ICS_ + CS_ + r];
}

// ---------------------------------------------------------------------------
// Conv gates: g[b,oc,s] = bias[oc] + sum_{ic,3x3} in[b,ic,y+dy,x+dx]*W[oc,ic,dy,dx]
// where in = concat(x_t, h*m). One thread per output element.
// ---------------------------------------------------------------------------
__global__ __launch_bounds__(256) void k_conv(const float* __restrict__ xt,
                                              const float* __restrict__ h,
                                              const float* __restrict__ W,
                                              const float* __restrict__ bias,
                                              const float* __restrict__ masks_t,
                                              int apply_mask,
                                              float* __restrict__ g) {
    int i = blockIdx.x * 256 + threadIdx.x;   // over B*OC*S = 802816
    if (i >= B_ * OCS_) return;
    int s  = i % S_;
    int oc = (i / S_) % OC_;
    int b  = i / OCS_;
    int y = s / HW_, x = s % HW_;

    const float* wbase = W + (size_t)oc * (IC_ * 9);
    const float* xb = xt + (size_t)b * CS_;
    const float* hb = h  + (size_t)b * CS_;

    float acc_x = 0.0f;
    float acc_h = 0.0f;

    // x-channel half (ic in [0,128))
    for (int ic = 0; ic < C_; ++ic) {
        const float* xc = xb + ic * S_;
        const float* wr = wbase + ic * 9;
        #pragma unroll
        for (int ky = 0; ky < 3; ++ky) {
            int yy = y + ky - 1;
            bool vy = (unsigned)yy < (unsigned)HW_;
            #pragma unroll
            for (int kx = 0; kx < 3; ++kx) {
                int xx = x + kx - 1;
                bool v = vy && ((unsigned)xx < (unsigned)HW_);
                float in = v ? xc[yy * HW_ + xx] : 0.0f;
                acc_x += in * wr[ky * 3 + kx];
            }
        }
    }
    // h-channel half (ic in [128,256)), mask folded in once at the end
    for (int ic = 0; ic < C_; ++ic) {
        const float* hc = hb + ic * S_;
        const float* wr = wbase + (C_ + ic) * 9;
        #pragma unroll
        for (int ky = 0; ky < 3; ++ky) {
            int yy = y + ky - 1;
            bool vy = (unsigned)yy < (unsigned)HW_;
            #pragma unroll
            for (int kx = 0; kx < 3; ++kx) {
                int xx = x + kx - 1;
                bool v = vy && ((unsigned)xx < (unsigned)HW_);
                float in = v ? hc[yy * HW_ + xx] : 0.0f;
                acc_h += in * wr[ky * 3 + kx];
            }
        }
    }
    float m = apply_mask ? masks_t[b] : 1.0f;
    g[i] = acc_x + m * acc_h + bias[oc];
}

// ---------------------------------------------------------------------------
// Gates: i,f,o,g nonlinearities + state update. c in-place, h in-place (conv
// that read h has already completed — separate dispatch).
// ---------------------------------------------------------------------------
__global__ __launch_bounds__(256) void k_gates(const float* __restrict__ g,
                                               float* __restrict__ c,
                                               float* __restrict__ h,
                                               const float* __restrict__ masks_t,
                                               int apply_mask) {
    int i = blockIdx.x * 256 + threadIdx.x;   // over B*C*S = 200704
    if (i >= B_ * CS_) return;
    int b = i / CS_;
    int r = i % CS_;
    size_t gi = (size_t)b * OCS_ + r;
    float ci = g[gi];
    float cf = g[gi + CS_];
    float co = g[gi + 2 * CS_];
    float cg = g[gi + 3 * CS_];
    float ig = sigm_f(ci);
    float fg = sigm_f(cf);
    float og = sigm_f(co);
    float gg = tanh_fast(cg);
    float c_old = c[i];
    if (apply_mask) c_old *= masks_t[b];
    float cn = fg * c_old + ig * gg;
    c[i] = cn;
    h[i] = og * tanh_fast(cn);
}

// ---------------------------------------------------------------------------
// Linear: out[b,n] = relu(sum_k c[b,k]*Wlin[n,k] + blin[n]); one wave/output.
// ---------------------------------------------------------------------------
__global__ __launch_bounds__(256) void k_linear(const float* __restrict__ c,
                                                const float* __restrict__ Wlin,
                                                const float* __restrict__ blin,
                                                float* __restrict__ out) {
    int wid  = (blockIdx.x * 256 + threadIdx.x) >> 6;   // global wave id
    int lane = threadIdx.x & 63;
    if (wid >= B_ * HS_) return;
    int b = wid / HS_;
    int n = wid % HS_;
    const float* cr = c    + (size_t)b * CS_;
    const float* wr = Wlin + (size_t)n * CS_;
    float acc = 0.0f;
    for (int k = lane; k < CS_; k += 64) acc += cr[k] * wr[k];
    #pragma unroll
    for (int off = 32; off > 0; off >>= 1) acc += __shfl_down(acc, off);
    if (lane == 0) out[(size_t)b * HS_ + n] = fmaxf(acc + blin[n], 0.0f);
}

// ---------------------------------------------------------------------------
// Final state: concat([hT, cT], axis=1) -> (B, 2C, 49)
// ---------------------------------------------------------------------------
__global__ __launch_bounds__(256) void k_final(const float* __restrict__ h,
                                               const float* __restrict__ c,
                                               float* __restrict__ out) {
    int i = blockIdx.x * 256 + threadIdx.x;   // over B*2C*S = 401408
    if (i >= B_ * ICS_) return;
    int b = i / ICS_;
    int r = i % ICS_;
    out[i] = (r < CS_) ? h[b * CS_ + r] : c[b * CS_ + (r - CS_)];
}

extern "C" void kernel_launch(void* const* d_in, const int* in_sizes, int n_in,
                              void* d_out, int out_size, void* d_ws, size_t ws_size,
                              hipStream_t stream) {
    const float* x     = (const float*)d_in[0];
    const float* hxs   = (const float*)d_in[1];
    const float* masks = (const float*)d_in[2];
    const float* Wconv = (const float*)d_in[3];
    const float* bconv = (const float*)d_in[4];
    const float* Wlin  = (const float*)d_in[5];
    const float* blin  = (const float*)d_in[6];
    float* out = (float*)d_out;

    float* ws   = (float*)d_ws;
    float* hbuf = ws;                 // 200704 floats
    float* cbuf = ws + 200704;        // 200704 floats
    float* gbuf = ws + 401408;        // 802816 floats  (total 4.82 MB)

    k_init<<<784, 256, 0, stream>>>(hxs, hbuf, cbuf);

    for (int t = 0; t < T_; ++t) {
        const float* xt = x + (size_t)t * B_ * CS_;
        const float* mt = masks + (size_t)t * B_;
        for (int rd = 0; rd < RD_; ++rd) {
            int am = (rd == 0) ? 1 : 0;
            k_conv<<<3136, 256, 0, stream>>>(xt, hbuf, Wconv, bconv, mt, am, gbuf);
            k_gates<<<784, 256, 0, stream>>>(gbuf, cbuf, hbuf, mt, am);
        }
        k_linear<<<4096, 256, 0, stream>>>(cbuf, Wlin, blin, out + (size_t)t * B_ * HS_);
    }

    k_final<<<1568, 256, 0, stream>>>(hbuf, cbuf, out + (size_t)T_ * B_ * HS_);
}

// Round 3
// 4043.138 us; speedup vs baseline: 19.7835x; 19.7835x over previous
//
#include <hip/hip_runtime.h>
#include <hip/hip_bf16.h>
#include <stdint.h>

#define T_  32
#define B_  32
#define C_  128
#define HS_ 512
#define HW_ 7
#define S_  49
#define CS_  (C_*S_)      // 6272
#define ICS_ (2*C_*S_)    // 12544
#define KC_  1152         // K of one conv half (128 ch * 9)
#define KF_  2304         // full conv K
#define KL_  6272         // linear K
#define M_   (B_*S_)      // 1568
#define N_   512

typedef __attribute__((ext_vector_type(8))) short short8;
typedef __attribute__((ext_vector_type(4))) float f32x4;
typedef __hip_bfloat16 bf16;

union bfbits { bf16 b; short s; };

__device__ __forceinline__ void gl16(const void* g, void* l) {
    __builtin_amdgcn_global_load_lds((const __attribute__((address_space(1))) void*)g,
                                     (__attribute__((address_space(3))) void*)l, 16, 0, 0);
}

// Stage a 64x64 bf16 tile of A and of B into LDS (linear dest, source-side XOR
// swizzle: LDS slot (r,kq) holds source chunk kq^(r&7); read applies same XOR).
__device__ __forceinline__ void stage64(
    const bf16* __restrict__ srcA, int strideA, int m0, int mmax, int kA0,
    const bf16* __restrict__ srcB, int strideB, int n0, int kB0,
    bf16* ldsA, bf16* ldsB, int w, int lane)
{
#pragma unroll
    for (int p = 0; p < 2; ++p) {
        int slot = p * 256 + w * 64 + lane;
        int r  = slot >> 3;
        int kq = slot & 7;
        int kqs = (kq ^ (r & 7)) << 3;            // source elem offset within row
        int ra = m0 + r; if (ra >= mmax) ra = 0;  // clamp (garbage rows unused)
        gl16(srcA + (size_t)ra * strideA + kA0 + kqs, ldsA + p * 2048 + w * 512);
        gl16(srcB + (size_t)(n0 + r) * strideB + kB0 + kqs, ldsB + p * 2048 + w * 512);
    }
}

// ---------------------------------------------------------------------------
// Fused conv-GEMM + LSTM gates + im2col(A_h) epilogue.
// C[m=(b,s)][n'=4c+gate] = Ax[m]·Wx[n'] + Ah[m]·Wh[n'] + bias
// ---------------------------------------------------------------------------
__global__ __launch_bounds__(256, 1) void k_fgemm(
    const bf16* __restrict__ Ax, const bf16* __restrict__ Ah,
    bf16* __restrict__ AhN, const bf16* __restrict__ Wp,
    const float* __restrict__ bconv,
    float* __restrict__ cbuf, float* __restrict__ hbuf,
    const float* __restrict__ mask_c, const float* __restrict__ mask_a,
    int write_ah, bf16* __restrict__ chist_t)
{
    __shared__ bf16 sA[2][64 * 64];
    __shared__ bf16 sB[2][64 * 64];
    __shared__ float gld[64][68];

    const int tid = threadIdx.x, lane = tid & 63, w = tid >> 6;
    const int wr = w >> 1, wc = w & 1;
    const int m0 = blockIdx.x * 64, n0 = blockIdx.y * 64;

    f32x4 acc[2][2];
#pragma unroll
    for (int fn = 0; fn < 2; ++fn) {
        int np = n0 + wc * 32 + fn * 16 + (lane & 15);
        float bv = bconv[((np & 3) << 7) + (np >> 2)];
        f32x4 b4 = {bv, bv, bv, bv};
        acc[0][fn] = b4; acc[1][fn] = b4;
    }

    auto stageFor = [&](int s2, bf16* lA, bf16* lB) {
        const bf16* As = (s2 < 18) ? Ax : Ah;
        int ka = ((s2 < 18) ? s2 : s2 - 18) * 64;
        stage64(As, KC_, m0, M_, ka, Wp, KF_, n0, s2 * 64, lA, lB, w, lane);
    };
    auto computeFrom = [&](const bf16* sAc, const bf16* sBc) {
        short8 af[2][2], bq[2][2];
#pragma unroll
        for (int f = 0; f < 2; ++f)
#pragma unroll
            for (int kh = 0; kh < 2; ++kh) {
                { int r = wr * 32 + f * 16 + (lane & 15);
                  int kc = kh * 4 + (lane >> 4);
                  af[f][kh] = *(const short8*)(sAc + r * 64 + ((kc ^ (r & 7)) << 3)); }
                { int r = wc * 32 + f * 16 + (lane & 15);
                  int kc = kh * 4 + (lane >> 4);
                  bq[f][kh] = *(const short8*)(sBc + r * 64 + ((kc ^ (r & 7)) << 3)); }
            }
#pragma unroll
        for (int kh = 0; kh < 2; ++kh)
#pragma unroll
            for (int fm = 0; fm < 2; ++fm)
#pragma unroll
                for (int fn = 0; fn < 2; ++fn)
                    acc[fm][fn] = __builtin_amdgcn_mfma_f32_16x16x32_bf16(
                        af[fm][kh], bq[fn][kh], acc[fm][fn], 0, 0, 0);
    };

    stageFor(0, sA[0], sB[0]);
    __syncthreads();

#pragma unroll 1
    for (int st = 0; st < 36; st += 2) {
        if (st + 1 < 36) stageFor(st + 1, sA[1], sB[1]);
        computeFrom(sA[0], sB[0]);
        __syncthreads();
        if (st + 2 < 36) stageFor(st + 2, sA[0], sB[0]);
        computeFrom(sA[1], sB[1]);   // 36 even -> st+1 always valid
        __syncthreads();
    }

    // ---- epilogue: acc -> LDS, then gates ----
#pragma unroll
    for (int fm = 0; fm < 2; ++fm)
#pragma unroll
        for (int fn = 0; fn < 2; ++fn) {
            int row = wr * 32 + fm * 16 + ((lane >> 4) << 2);
            int col = wc * 32 + fn * 16 + (lane & 15);
#pragma unroll
            for (int j = 0; j < 4; ++j) gld[row + j][col] = acc[fm][fn][j];
        }
    __syncthreads();

#pragma unroll 1
    for (int q = 0; q < 4; ++q) {
        int e = tid * 4 + q;
        int row = e >> 4, cc = e & 15;
        int m = m0 + row;
        if (m >= M_) continue;
        int b = m / S_, s = m % S_;
        int y = s / HW_, x = s % HW_;
        int cg = (n0 >> 2) + cc;
        float g0 = gld[row][cc * 4 + 0], g1 = gld[row][cc * 4 + 1];
        float g2 = gld[row][cc * 4 + 2], g3 = gld[row][cc * 4 + 3];
        float ig = 1.f / (1.f + expf(-g0));
        float fg = 1.f / (1.f + expf(-g1));
        float og = 1.f / (1.f + expf(-g2));
        float gg = tanhf(g3);
        size_t cidx = (size_t)(b * C_ + cg) * S_ + s;
        float co = cbuf[cidx];
        if (mask_c) co *= mask_c[b];
        float cn = fg * co + ig * gg;
        cbuf[cidx] = cn;
        float hn = og * tanhf(cn);
        hbuf[cidx] = hn;
        if (chist_t) chist_t[(size_t)b * KL_ + cg * S_ + s] = __float2bfloat16(cn);
        if (write_ah) {
            float am = mask_a ? mask_a[b] : 1.f;
            bf16 hv = __float2bfloat16(hn * am);
#pragma unroll
            for (int dy = -1; dy <= 1; ++dy) {
                int y2 = y + dy; if ((unsigned)y2 >= (unsigned)HW_) continue;
#pragma unroll
                for (int dx = -1; dx <= 1; ++dx) {
                    int x2 = x + dx; if ((unsigned)x2 >= (unsigned)HW_) continue;
                    AhN[(size_t)(b * S_ + y2 * HW_ + x2) * KC_ + cg * 9 + (1 - dy) * 3 + (1 - dx)] = hv;
                }
            }
        }
    }
}

// ---------------------------------------------------------------------------
// Deferred linear: out[(t,b)][n] = relu(chist[(t,b)]·Wlin[n] + blin[n])
// ---------------------------------------------------------------------------
__global__ __launch_bounds__(256, 1) void k_lingemm(
    const bf16* __restrict__ Ac, const bf16* __restrict__ Wl,
    const float* __restrict__ blin, float* __restrict__ out)
{
    __shared__ bf16 sA[2][64 * 64];
    __shared__ bf16 sB[2][64 * 64];

    const int tid = threadIdx.x, lane = tid & 63, w = tid >> 6;
    const int wr = w >> 1, wc = w & 1;
    const int m0 = blockIdx.x * 64, n0 = blockIdx.y * 64;

    f32x4 acc[2][2];
#pragma unroll
    for (int fn = 0; fn < 2; ++fn) {
        int np = n0 + wc * 32 + fn * 16 + (lane & 15);
        float bv = blin[np];
        f32x4 b4 = {bv, bv, bv, bv};
        acc[0][fn] = b4; acc[1][fn] = b4;
    }

    auto stageFor = [&](int s2, bf16* lA, bf16* lB) {
        stage64(Ac, KL_, m0, 1024, s2 * 64, Wl, KL_, n0, s2 * 64, lA, lB, w, lane);
    };
    auto computeFrom = [&](const bf16* sAc, const bf16* sBc) {
        short8 af[2][2], bq[2][2];
#pragma unroll
        for (int f = 0; f < 2; ++f)
#pragma unroll
            for (int kh = 0; kh < 2; ++kh) {
                { int r = wr * 32 + f * 16 + (lane & 15);
                  int kc = kh * 4 + (lane >> 4);
                  af[f][kh] = *(const short8*)(sAc + r * 64 + ((kc ^ (r & 7)) << 3)); }
                { int r = wc * 32 + f * 16 + (lane & 15);
                  int kc = kh * 4 + (lane >> 4);
                  bq[f][kh] = *(const short8*)(sBc + r * 64 + ((kc ^ (r & 7)) << 3)); }
            }
#pragma unroll
        for (int kh = 0; kh < 2; ++kh)
#pragma unroll
            for (int fm = 0; fm < 2; ++fm)
#pragma unroll
                for (int fn = 0; fn < 2; ++fn)
                    acc[fm][fn] = __builtin_amdgcn_mfma_f32_16x16x32_bf16(
                        af[fm][kh], bq[fn][kh], acc[fm][fn], 0, 0, 0);
    };

    stageFor(0, sA[0], sB[0]);
    __syncthreads();

#pragma unroll 1
    for (int st = 0; st < 98; st += 2) {
        if (st + 1 < 98) stageFor(st + 1, sA[1], sB[1]);
        computeFrom(sA[0], sB[0]);
        __syncthreads();
        if (st + 2 < 98) stageFor(st + 2, sA[0], sB[0]);
        computeFrom(sA[1], sB[1]);   // 98 even
        __syncthreads();
    }

#pragma unroll
    for (int fm = 0; fm < 2; ++fm)
#pragma unroll
        for (int fn = 0; fn < 2; ++fn) {
            int col = n0 + wc * 32 + fn * 16 + (lane & 15);
            int rb  = m0 + wr * 32 + fm * 16 + ((lane >> 4) << 2);
#pragma unroll
            for (int j = 0; j < 4; ++j)
                out[(size_t)(rb + j) * N_ + col] = fmaxf(acc[fm][fn][j], 0.f);
        }
}

// ---------------------------------------------------------------------------
// im2col (output-centric, full write incl. zeros): dst[m=(b,s)][k=ic*9+kid]
// = src[b][ic][y+ky-1][x+kx-1]*mask  (0 if OOB)
// ---------------------------------------------------------------------------
__global__ __launch_bounds__(256) void k_im2col(const float* __restrict__ src, int bstride,
                                                const float* __restrict__ mask,
                                                bf16* __restrict__ dst)
{
    int idx = blockIdx.x * 256 + threadIdx.x;
    if (idx >= M_ * 144) return;
    int m = idx / 144, kq = idx % 144;
    int b = m / S_, s = m % S_;
    int y = s / HW_, x = s % HW_;
    float mk = mask ? mask[b] : 1.f;
    const float* sb = src + (size_t)b * bstride;
    short8 v;
#pragma unroll
    for (int j = 0; j < 8; ++j) {
        int k = kq * 8 + j;
        int ic = k / 9, kid = k % 9;
        int ky = kid / 3, kx = kid % 3;
        int yy = y + ky - 1, xc = x + kx - 1;
        float f = 0.f;
        if ((unsigned)yy < (unsigned)HW_ && (unsigned)xc < (unsigned)HW_)
            f = sb[ic * S_ + yy * HW_ + xc] * mk;
        bfbits bb; bb.b = __float2bfloat16(f);
        v[j] = bb.s;
    }
    *reinterpret_cast<short8*>(dst + (size_t)m * KC_ + kq * 8) = v;
}

// Weight prep: Wp[n'=4c+gate][k] bf16, k<1152 -> x-half (ic=k/9), else h-half.
__global__ __launch_bounds__(256) void k_wconv(const float* __restrict__ Wc, bf16* __restrict__ Wp) {
    int idx = blockIdx.x * 256 + threadIdx.x;
    if (idx >= 512 * 288) return;
    int np = idx / 288, kq = idx % 288;
    int oc = ((np & 3) << 7) + (np >> 2);
    short8 v;
#pragma unroll
    for (int j = 0; j < 8; ++j) {
        int k = kq * 8 + j;
        int ic, kid;
        if (k < KC_) { ic = k / 9; kid = k % 9; }
        else { int k2 = k - KC_; ic = 128 + k2 / 9; kid = k2 % 9; }
        bfbits bb; bb.b = __float2bfloat16(Wc[((size_t)oc * 256 + ic) * 9 + kid]);
        v[j] = bb.s;
    }
    *reinterpret_cast<short8*>(Wp + (size_t)np * KF_ + kq * 8) = v;
}

__global__ __launch_bounds__(256) void k_wlin(const float* __restrict__ Wl, bf16* __restrict__ Wp) {
    int idx = blockIdx.x * 256 + threadIdx.x;
    if (idx >= 512 * 784) return;
    int np = idx / 784, kq = idx % 784;
    short8 v;
#pragma unroll
    for (int j = 0; j < 8; ++j) {
        bfbits bb; bb.b = __float2bfloat16(Wl[(size_t)np * KL_ + kq * 8 + j]);
        v[j] = bb.s;
    }
    *reinterpret_cast<short8*>(Wp + (size_t)np * KL_ + kq * 8) = v;
}

__global__ __launch_bounds__(256) void k_initc(const float* __restrict__ hxs, float* __restrict__ cbuf) {
    int i = blockIdx.x * 256 + threadIdx.x;
    if (i >= B_ * CS_) return;
    int b = i / CS_, r = i % CS_;
    cbuf[i] = hxs[(size_t)b * ICS_ + CS_ + r];
}

__global__ __launch_bounds__(256) void k_zero16(uint4* __restrict__ p, int n) {
    int i = blockIdx.x * 256 + threadIdx.x;
    if (i < n) p[i] = make_uint4(0, 0, 0, 0);
}

__global__ __launch_bounds__(256) void k_final(const float* __restrict__ h, const float* __restrict__ c,
                                               float* __restrict__ out) {
    int i = blockIdx.x * 256 + threadIdx.x;
    if (i >= B_ * ICS_) return;
    int b = i / ICS_, r = i % ICS_;
    out[i] = (r < CS_) ? h[(size_t)b * CS_ + r] : c[(size_t)b * CS_ + (r - CS_)];
}

extern "C" void kernel_launch(void* const* d_in, const int* in_sizes, int n_in,
                              void* d_out, int out_size, void* d_ws, size_t ws_size,
                              hipStream_t stream) {
    (void)in_sizes; (void)n_in; (void)out_size; (void)ws_size;
    const float* x     = (const float*)d_in[0];
    const float* hxs   = (const float*)d_in[1];
    const float* masks = (const float*)d_in[2];
    const float* Wconv = (const float*)d_in[3];
    const float* bconv = (const float*)d_in[4];
    const float* Wlin  = (const float*)d_in[5];
    const float* blin  = (const float*)d_in[6];
    float* out = (float*)d_out;

    uint8_t* p = (uint8_t*)d_ws;
    bf16* Wp    = (bf16*)p;                 p += (size_t)512 * KF_ * 2;      // 2.36 MB
    bf16* Wlp   = (bf16*)p;                 p += (size_t)512 * KL_ * 2;      // 6.42 MB
    bf16* Axb   = (bf16*)p;                 p += (size_t)M_ * KC_ * 2;       // 3.61 MB
    bf16* Ah0   = (bf16*)p;                 p += (size_t)M_ * KC_ * 2;
    bf16* Ah1   = (bf16*)p;                 p += (size_t)M_ * KC_ * 2;
    bf16* chist = (bf16*)p;                 p += (size_t)1024 * KL_ * 2;     // 12.8 MB
    float* cbuf = (float*)p;                p += (size_t)B_ * CS_ * 4;
    float* hbuf = (float*)p;                p += (size_t)B_ * CS_ * 4;
    bf16* AhBuf[2] = {Ah0, Ah1};

    k_wconv<<<576, 256, 0, stream>>>(Wconv, Wp);
    k_wlin<<<1568, 256, 0, stream>>>(Wlin, Wlp);
    k_initc<<<784, 256, 0, stream>>>(hxs, cbuf);
    k_zero16<<<882, 256, 0, stream>>>((uint4*)Ah1, (int)((size_t)M_ * KC_ * 2 / 16));
    k_im2col<<<882, 256, 0, stream>>>(hxs, ICS_, masks, Ah0);   // h0 * mask[0]

    int g = 0;
    for (int t = 0; t < T_; ++t) {
        k_im2col<<<882, 256, 0, stream>>>(x + (size_t)t * B_ * CS_, CS_, nullptr, Axb);
        for (int rd = 0; rd < 3; ++rd) {
            const float* mc = (rd == 0) ? masks + (size_t)t * B_ : nullptr;
            const float* ma = (rd == 2 && t < T_ - 1) ? masks + (size_t)(t + 1) * B_ : nullptr;
            int wah = !(t == T_ - 1 && rd == 2);
            bf16* ct = (rd == 2) ? chist + (size_t)t * B_ * KL_ : nullptr;
            k_fgemm<<<dim3(25, 8), 256, 0, stream>>>(
                Axb, AhBuf[g & 1], AhBuf[(g + 1) & 1], Wp, bconv,
                cbuf, hbuf, mc, ma, wah, ct);
            ++g;
        }
    }

    k_lingemm<<<dim3(16, 8), 256, 0, stream>>>(chist, Wlp, blin, out);
    k_final<<<1568, 256, 0, stream>>>(hbuf, cbuf, out + (size_t)T_ * B_ * HS_);
}

// Round 4
// 1713.928 us; speedup vs baseline: 46.6690x; 2.3590x over previous
//
#include <hip/hip_runtime.h>
#include <hip/hip_bf16.h>
#include <stdint.h>

#define T_  32
#define B_  32
#define C_  128
#define HS_ 512
#define HW_ 7
#define S_  49
#define CS_  (C_*S_)      // 6272
#define ICS_ (2*C_*S_)    // 12544
#define KH_  1152         // per-half conv K (9*128), kid-major: k = kid*128+ic
#define KL_  6272         // linear K, reordered to k' = s*128+c
#define M_   1568         // B*S
#define N_   512

typedef __attribute__((ext_vector_type(8))) short short8;
typedef __attribute__((ext_vector_type(4))) float f32x4;
typedef __hip_bfloat16 bf16;

union bfbits { bf16 b; short s; };

__device__ __forceinline__ void gl16(const void* g, void* l) {
    __builtin_amdgcn_global_load_lds((const __attribute__((address_space(1))) void*)g,
                                     (__attribute__((address_space(3))) void*)l, 16, 0, 0);
}

__device__ __forceinline__ float sigm_f(float v) { return 1.0f / (1.0f + __expf(-v)); }
__device__ __forceinline__ float tanh_f(float v) { return 1.0f - 2.0f / (__expf(2.0f * v) + 1.0f); }

// ---------------------------------------------------------------------------
// Fused conv-GEMM + LSTM gates. Tile 32x64, 4 waves (each wave: 32x16 out).
// mode0 (rd==0): C = Ax*Wx + Ah*Wh + bias over 36 K-steps (two accumulators),
//   stores Gx = Ax*Wx + bias for reuse by rd1/rd2.
// mode1: C = Gx + Ah*Wh over 18 K-steps.
// A staged on-the-fly from (b,s,c) bf16 layout: row (b,s), K-step (kid,koff)
// reads 64 contiguous channels at spatially-shifted row base (OOB -> zb).
// ---------------------------------------------------------------------------
__global__ __launch_bounds__(256, 2) void k_fgemm(
    const bf16* __restrict__ xTt, const bf16* __restrict__ hT,
    bf16* __restrict__ hTN,
    const bf16* __restrict__ WxP, const bf16* __restrict__ WhP,
    const float* __restrict__ bconv,
    float* __restrict__ Gx, float* __restrict__ cbuf,
    const float* __restrict__ mask_c, const float* __restrict__ mask_a,
    bf16* __restrict__ chist_t, const bf16* __restrict__ zb, int mode0)
{
    __shared__ bf16 sA[2][32 * 64];
    __shared__ bf16 sB[2][64 * 64];
    __shared__ float gld[32][68];

    const int tid = threadIdx.x, lane = tid & 63, w = tid >> 6;
    const int m0 = blockIdx.x * 32, n0 = blockIdx.y * 64;

    // A staging: one row per thread (32 rows x 8 chunks = 256 slots)
    const int ar   = tid >> 3;
    const int akq  = tid & 7;
    const int am_  = m0 + ar;
    const int ab   = am_ / S_;
    const int as_  = am_ % S_;
    const int ayy  = as_ / HW_, axx = as_ % HW_;
    const int aswz = ((akq ^ (ar & 7)) << 3);

    // B staging: 64 rows x 8 chunks = 512 slots (2 per thread)
    const int br0 = tid >> 3;
    const int br1 = (256 + tid) >> 3;
    const int bswz0 = (((tid & 7) ^ (br0 & 7)) << 3);
    const int bswz1 = (((tid & 7) ^ (br1 & 7)) << 3);

    const int NS = mode0 ? 36 : 18;

    f32x4 accX[2], accH[2];
    if (mode0) {
        int np = n0 + w * 16 + (lane & 15);
        float bv = bconv[((np & 3) << 7) + (np >> 2)];
        f32x4 b4 = {bv, bv, bv, bv};
        accX[0] = b4; accX[1] = b4;
        f32x4 z4 = {0.f, 0.f, 0.f, 0.f};
        accH[0] = z4; accH[1] = z4;
    } else {
#pragma unroll
        for (int fm = 0; fm < 2; ++fm) {
            int row = m0 + fm * 16 + ((lane >> 4) << 2);
            int col = n0 + w * 16 + (lane & 15);
#pragma unroll
            for (int j = 0; j < 4; ++j) accH[fm][j] = Gx[(size_t)(row + j) * N_ + col];
        }
    }

    auto stageFor = [&](int st, bf16* lA, bf16* lB) {
        int xphase = (mode0 && st < 18);
        int stl = (mode0 && st >= 18) ? st - 18 : st;
        int kid = stl >> 1, koff = (stl & 1) << 6;
        int ky = kid / 3, kx = kid - ky * 3;
        int y2 = ayy + ky - 1, x2 = axx + kx - 1;
        const bf16* Asrc = xphase ? xTt : hT;
        const bf16* rbase;
        if ((unsigned)y2 < (unsigned)HW_ && (unsigned)x2 < (unsigned)HW_)
            rbase = Asrc + (((size_t)ab * S_ + y2 * HW_ + x2) << 7) + koff;
        else
            rbase = zb;
        gl16(rbase + aswz, lA + w * 512);
        const bf16* Wsrc = xphase ? WxP : WhP;
        gl16(Wsrc + (size_t)(n0 + br0) * KH_ + stl * 64 + bswz0, lB + w * 512);
        gl16(Wsrc + (size_t)(n0 + br1) * KH_ + stl * 64 + bswz1, lB + 2048 + w * 512);
    };

    auto computeFrom = [&](const bf16* sAc, const bf16* sBc, f32x4 (&acc)[2]) {
        short8 af[2][2], bq[2];
#pragma unroll
        for (int kh = 0; kh < 2; ++kh) {
#pragma unroll
            for (int fm = 0; fm < 2; ++fm) {
                int r = fm * 16 + (lane & 15);
                int kc = kh * 4 + (lane >> 4);
                af[fm][kh] = *(const short8*)(sAc + r * 64 + ((kc ^ (r & 7)) << 3));
            }
            { int r = w * 16 + (lane & 15);
              int kc = kh * 4 + (lane >> 4);
              bq[kh] = *(const short8*)(sBc + r * 64 + ((kc ^ (r & 7)) << 3)); }
        }
#pragma unroll
        for (int kh = 0; kh < 2; ++kh)
#pragma unroll
            for (int fm = 0; fm < 2; ++fm)
                acc[fm] = __builtin_amdgcn_mfma_f32_16x16x32_bf16(af[fm][kh], bq[kh], acc[fm], 0, 0, 0);
    };

    stageFor(0, sA[0], sB[0]);
    __syncthreads();

#pragma unroll 1
    for (int st = 0; st < NS; st += 2) {
        if (st + 1 < NS) stageFor(st + 1, sA[1], sB[1]);
        if (mode0 && st < 18) computeFrom(sA[0], sB[0], accX);
        else                  computeFrom(sA[0], sB[0], accH);
        __syncthreads();
        if (st + 2 < NS) stageFor(st + 2, sA[0], sB[0]);
        if (mode0 && st + 1 < 18) computeFrom(sA[1], sB[1], accX);
        else                      computeFrom(sA[1], sB[1], accH);   // NS even
        __syncthreads();
    }

    if (mode0) {
#pragma unroll
        for (int fm = 0; fm < 2; ++fm) {
            int row = m0 + fm * 16 + ((lane >> 4) << 2);
            int col = n0 + w * 16 + (lane & 15);
#pragma unroll
            for (int j = 0; j < 4; ++j) {
                Gx[(size_t)(row + j) * N_ + col] = accX[fm][j];
                accH[fm][j] += accX[fm][j];
            }
        }
    }

#pragma unroll
    for (int fm = 0; fm < 2; ++fm) {
        int row = fm * 16 + ((lane >> 4) << 2);
        int col = w * 16 + (lane & 15);
#pragma unroll
        for (int j = 0; j < 4; ++j) gld[row + j][col] = accH[fm][j];
    }
    __syncthreads();

#pragma unroll
    for (int q = 0; q < 2; ++q) {
        int e = tid * 2 + q;
        int row = e >> 4, cc = e & 15;
        int m = m0 + row;
        int b = m / S_, s = m % S_;
        int cg = (n0 >> 2) + cc;
        float g0 = gld[row][cc * 4 + 0], g1 = gld[row][cc * 4 + 1];
        float g2 = gld[row][cc * 4 + 2], g3 = gld[row][cc * 4 + 3];
        float ig = sigm_f(g0);
        float fg = sigm_f(g1);
        float og = sigm_f(g2);
        float gg = tanh_f(g3);
        size_t ci = (((size_t)b * S_ + s) << 7) + cg;
        float co = cbuf[ci];
        if (mask_c) co *= mask_c[b];
        float cn = fg * co + ig * gg;
        cbuf[ci] = cn;
        float hn = og * tanh_f(cn);
        float am = mask_a ? mask_a[b] : 1.f;
        hTN[ci] = __float2bfloat16(hn * am);
        if (chist_t) chist_t[(size_t)b * KL_ + s * C_ + cg] = __float2bfloat16(cn);
    }
}

// ---------------------------------------------------------------------------
// Staging helper for the linear GEMM (contiguous K rows, XOR-swizzled chunks)
// ---------------------------------------------------------------------------
__device__ __forceinline__ void stage64(
    const bf16* __restrict__ srcA, int strideA, int m0, int kA0,
    const bf16* __restrict__ srcB, int strideB, int n0, int kB0,
    bf16* ldsA, bf16* ldsB, int w, int lane)
{
#pragma unroll
    for (int p = 0; p < 2; ++p) {
        int slot = p * 256 + w * 64 + lane;
        int r  = slot >> 3;
        int kq = slot & 7;
        int kqs = (kq ^ (r & 7)) << 3;
        gl16(srcA + (size_t)(m0 + r) * strideA + kA0 + kqs, ldsA + p * 2048 + w * 512);
        gl16(srcB + (size_t)(n0 + r) * strideB + kB0 + kqs, ldsB + p * 2048 + w * 512);
    }
}

// Deferred linear: out[(t,b)][n] = relu(chist[(t,b)]·Wlp[n] + blin[n]), 64x64 tile
__global__ __launch_bounds__(256, 2) void k_lingemm(
    const bf16* __restrict__ Ac, const bf16* __restrict__ Wl,
    const float* __restrict__ blin, float* __restrict__ out)
{
    __shared__ bf16 sA[2][64 * 64];
    __shared__ bf16 sB[2][64 * 64];

    const int tid = threadIdx.x, lane = tid & 63, w = tid >> 6;
    const int wr = w >> 1, wc = w & 1;
    const int m0 = blockIdx.x * 64, n0 = blockIdx.y * 64;

    f32x4 acc[2][2];
#pragma unroll
    for (int fn = 0; fn < 2; ++fn) {
        int np = n0 + wc * 32 + fn * 16 + (lane & 15);
        float bv = blin[np];
        f32x4 b4 = {bv, bv, bv, bv};
        acc[0][fn] = b4; acc[1][fn] = b4;
    }

    auto stageFor = [&](int s2, bf16* lA, bf16* lB) {
        stage64(Ac, KL_, m0, s2 * 64, Wl, KL_, n0, s2 * 64, lA, lB, w, lane);
    };
    auto computeFrom = [&](const bf16* sAc, const bf16* sBc) {
        short8 af[2][2], bq[2][2];
#pragma unroll
        for (int f = 0; f < 2; ++f)
#pragma unroll
            for (int kh = 0; kh < 2; ++kh) {
                { int r = wr * 32 + f * 16 + (lane & 15);
                  int kc = kh * 4 + (lane >> 4);
                  af[f][kh] = *(const short8*)(sAc + r * 64 + ((kc ^ (r & 7)) << 3)); }
                { int r = wc * 32 + f * 16 + (lane & 15);
                  int kc = kh * 4 + (lane >> 4);
                  bq[f][kh] = *(const short8*)(sBc + r * 64 + ((kc ^ (r & 7)) << 3)); }
            }
#pragma unroll
        for (int kh = 0; kh < 2; ++kh)
#pragma unroll
            for (int fm = 0; fm < 2; ++fm)
#pragma unroll
                for (int fn = 0; fn < 2; ++fn)
                    acc[fm][fn] = __builtin_amdgcn_mfma_f32_16x16x32_bf16(
                        af[fm][kh], bq[fn][kh], acc[fm][fn], 0, 0, 0);
    };

    stageFor(0, sA[0], sB[0]);
    __syncthreads();

#pragma unroll 1
    for (int st = 0; st < 98; st += 2) {
        if (st + 1 < 98) stageFor(st + 1, sA[1], sB[1]);
        computeFrom(sA[0], sB[0]);
        __syncthreads();
        if (st + 2 < 98) stageFor(st + 2, sA[0], sB[0]);
        computeFrom(sA[1], sB[1]);   // 98 even
        __syncthreads();
    }

#pragma unroll
    for (int fm = 0; fm < 2; ++fm)
#pragma unroll
        for (int fn = 0; fn < 2; ++fn) {
            int col = n0 + wc * 32 + fn * 16 + (lane & 15);
            int rb  = m0 + wr * 32 + fm * 16 + ((lane >> 4) << 2);
#pragma unroll
            for (int j = 0; j < 4; ++j)
                out[(size_t)(rb + j) * N_ + col] = fmaxf(acc[fm][fn][j], 0.f);
        }
}

// ---------------------------------------------------------------------------
// Weight prep: split Wconv into Wx/Wh, n' = 4c+gate rows, k = kid*128+ic
// ---------------------------------------------------------------------------
__global__ __launch_bounds__(256) void k_wsplit(const float* __restrict__ Wc,
                                               bf16* __restrict__ WxP, bf16* __restrict__ WhP) {
    int idx = blockIdx.x * 256 + threadIdx.x;     // 512*288
    if (idx >= 512 * 288) return;
    int np = idx / 288, kq = idx % 288;
    int oc = ((np & 3) << 7) + (np >> 2);
    int kk = kq * 8;
    int half = kk >= KH_;
    int krel = kk - half * KH_;
    short8 v;
#pragma unroll
    for (int j = 0; j < 8; ++j) {
        int kr = krel + j;
        int kid = kr >> 7, ic = (kr & 127) + half * 128;
        bfbits bb; bb.b = __float2bfloat16(Wc[((size_t)oc * 256 + ic) * 9 + kid]);
        v[j] = bb.s;
    }
    bf16* dst = half ? WhP : WxP;
    *reinterpret_cast<short8*>(dst + (size_t)np * KH_ + krel) = v;
}

// Wlin reorder: k' = s*128+c
__global__ __launch_bounds__(256) void k_wlin2(const float* __restrict__ Wl, bf16* __restrict__ Wp) {
    int idx = blockIdx.x * 256 + threadIdx.x;     // 512*784
    if (idx >= 512 * 784) return;
    int np = idx / 784, kq = idx % 784;
    short8 v;
#pragma unroll
    for (int j = 0; j < 8; ++j) {
        int kp = kq * 8 + j;
        int s = kp >> 7, c = kp & 127;
        bfbits bb; bb.b = __float2bfloat16(Wl[(size_t)np * KL_ + c * S_ + s]);
        v[j] = bb.s;
    }
    *reinterpret_cast<short8*>(Wp + (size_t)np * KL_ + kq * 8) = v;
}

// x (T*B, C, 49) f32 -> xT (T*B, 49, 128) bf16
__global__ __launch_bounds__(256) void k_xpose(const float* __restrict__ x, bf16* __restrict__ xT) {
    int idx = blockIdx.x * 256 + threadIdx.x;     // 1024*784
    if (idx >= 1024 * 784) return;
    int r = idx / 784;
    int rem = idx % 784;
    int s = rem / 16, c8 = (rem & 15) * 8;
    const float* sp = x + (size_t)r * CS_ + c8 * S_ + s;
    short8 v;
#pragma unroll
    for (int j = 0; j < 8; ++j) { bfbits bb; bb.b = __float2bfloat16(sp[j * S_]); v[j] = bb.s; }
    *reinterpret_cast<short8*>(xT + (((size_t)r * S_ + s) << 7) + c8) = v;
}

// h0*mask0 -> hT bf16 (b,s,c);  c0 -> cbuf f32 (b,s,c)
__global__ __launch_bounds__(256) void k_hcprep(const float* __restrict__ hxs,
                                                const float* __restrict__ mask0,
                                                bf16* __restrict__ hT, float* __restrict__ cbuf) {
    int idx = blockIdx.x * 256 + threadIdx.x;     // 32*784
    if (idx >= 32 * 784) return;
    int b = idx / 784;
    int rem = idx % 784;
    int s = rem / 16, c8 = (rem & 15) * 8;
    float m = mask0[b];
    const float* hp = hxs + (size_t)b * ICS_ + c8 * S_ + s;
    const float* cp = hp + CS_;
    size_t o = (((size_t)b * S_ + s) << 7) + c8;
    short8 v;
#pragma unroll
    for (int j = 0; j < 8; ++j) {
        bfbits bb; bb.b = __float2bfloat16(hp[j * S_] * m); v[j] = bb.s;
        cbuf[o + j] = cp[j * S_];
    }
    *reinterpret_cast<short8*>(hT + o) = v;
}

__global__ __launch_bounds__(256) void k_zero16(uint4* __restrict__ p, int n) {
    int i = blockIdx.x * 256 + threadIdx.x;
    if (i < n) p[i] = make_uint4(0, 0, 0, 0);
}

// final state: out[b][ch][s], ch<128 from hT bf16, else cbuf f32 (both (b,s,c))
__global__ __launch_bounds__(256) void k_final(const bf16* __restrict__ hT, const float* __restrict__ cbuf,
                                               float* __restrict__ out) {
    int i = blockIdx.x * 256 + threadIdx.x;       // 32*12544
    if (i >= B_ * ICS_) return;
    int b = i / ICS_, r = i % ICS_;
    int ch = r / S_, s = r % S_;
    size_t o = (((size_t)b * S_ + s) << 7);
    out[i] = (ch < C_) ? __bfloat162float(hT[o + ch]) : cbuf[o + (ch - C_)];
}

extern "C" void kernel_launch(void* const* d_in, const int* in_sizes, int n_in,
                              void* d_out, int out_size, void* d_ws, size_t ws_size,
                              hipStream_t stream) {
    (void)in_sizes; (void)n_in; (void)out_size; (void)ws_size;
    const float* x     = (const float*)d_in[0];
    const float* hxs   = (const float*)d_in[1];
    const float* masks = (const float*)d_in[2];
    const float* Wconv = (const float*)d_in[3];
    const float* bconv = (const float*)d_in[4];
    const float* Wlin  = (const float*)d_in[5];
    const float* blin  = (const float*)d_in[6];
    float* out = (float*)d_out;

    uint8_t* p = (uint8_t*)d_ws;
    bf16* WxP   = (bf16*)p;   p += (size_t)512 * KH_ * 2;        // 1.18 MB
    bf16* WhP   = (bf16*)p;   p += (size_t)512 * KH_ * 2;        // 1.18 MB
    bf16* Wlp   = (bf16*)p;   p += (size_t)512 * KL_ * 2;        // 6.42 MB
    bf16* xT    = (bf16*)p;   p += (size_t)1024 * S_ * C_ * 2;   // 12.85 MB
    bf16* hA    = (bf16*)p;   p += (size_t)B_ * S_ * C_ * 2;     // 0.40 MB
    bf16* hB    = (bf16*)p;   p += (size_t)B_ * S_ * C_ * 2;     // 0.40 MB
    float* cbuf = (float*)p;  p += (size_t)B_ * S_ * C_ * 4;     // 0.80 MB
    float* Gx   = (float*)p;  p += (size_t)M_ * N_ * 4;          // 3.21 MB
    bf16* chist = (bf16*)p;   p += (size_t)1024 * KL_ * 2;       // 12.85 MB
    bf16* zb    = (bf16*)p;   p += 1024;                         // zero page
    bf16* hbufs[2] = {hA, hB};

    k_wsplit<<<576, 256, 0, stream>>>(Wconv, WxP, WhP);
    k_wlin2<<<1568, 256, 0, stream>>>(Wlin, Wlp);
    k_xpose<<<3136, 256, 0, stream>>>(x, xT);
    k_hcprep<<<98, 256, 0, stream>>>(hxs, masks, hA, cbuf);
    k_zero16<<<1, 256, 0, stream>>>((uint4*)zb, 64);

    int g = 0;
    for (int t = 0; t < T_; ++t) {
        const bf16* xTt = xT + (size_t)t * B_ * S_ * C_;
        for (int rd = 0; rd < 3; ++rd) {
            const float* mc = (rd == 0) ? masks + (size_t)t * B_ : nullptr;
            const float* ma = (rd == 2 && t < T_ - 1) ? masks + (size_t)(t + 1) * B_ : nullptr;
            bf16* ct = (rd == 2) ? chist + (size_t)t * B_ * KL_ : nullptr;
            k_fgemm<<<dim3(49, 8), 256, 0, stream>>>(
                (rd == 0) ? xTt : nullptr, hbufs[g & 1], hbufs[(g + 1) & 1],
                WxP, WhP, bconv, Gx, cbuf, mc, ma, ct, zb, (rd == 0) ? 1 : 0);
            ++g;
        }
    }

    k_lingemm<<<dim3(16, 8), 256, 0, stream>>>(chist, Wlp, blin, out);
    k_final<<<1568, 256, 0, stream>>>(hbufs[0], cbuf, out + (size_t)T_ * B_ * HS_);
}

// Round 5
// 1403.173 us; speedup vs baseline: 57.0046x; 1.2215x over previous
//
#include <hip/hip_runtime.h>
#include <hip/hip_bf16.h>
#include <stdint.h>

#define T_  32
#define B_  32
#define C_  128
#define HS_ 512
#define HW_ 7
#define S_  49
#define CS_  (C_*S_)      // 6272
#define ICS_ (2*C_*S_)    // 12544
#define KH_  1152         // per-half conv K (9*128), kid-major: k = kid*128+ic
#define KL_  6272         // linear K, reordered to k' = s*128+c
#define M_   1568         // B*S
#define MR_  1600         // M rounded to 64
#define N_   512

typedef __attribute__((ext_vector_type(8))) short short8;
typedef __attribute__((ext_vector_type(4))) float f32x4;
typedef __hip_bfloat16 bf16;

union bfbits { bf16 b; short s; };

__device__ __forceinline__ void gl16(const void* g, void* l) {
    __builtin_amdgcn_global_load_lds((const __attribute__((address_space(1))) void*)g,
                                     (__attribute__((address_space(3))) void*)l, 16, 0, 0);
}

__device__ __forceinline__ float sigm_f(float v) { return 1.0f / (1.0f + __expf(-v)); }
__device__ __forceinline__ float tanh_f(float v) { return 1.0f - 2.0f / (__expf(2.0f * v) + 1.0f); }

// ---------------------------------------------------------------------------
// Fused conv-GEMM + LSTM gates. Tile 64x64, 4 waves (2x2), BK=128 (1 K-step
// = one 3x3 tap = contiguous 128-ch read/row). 1 barrier per K-step.
// mode0: C = Ax*Wx + Ah*Wh + bias (18 steps, two accumulators, stores Gx).
// mode1: C = Gx + Ah*Wh (9 steps).
// ---------------------------------------------------------------------------
__global__ __launch_bounds__(256, 2) void k_fgemm(
    const bf16* __restrict__ xTt, const bf16* __restrict__ hT,
    bf16* __restrict__ hTN,
    const bf16* __restrict__ WxP, const bf16* __restrict__ WhP,
    const float* __restrict__ bconv,
    float* __restrict__ Gx, float* __restrict__ cbuf,
    const float* __restrict__ mask_c, const float* __restrict__ mask_a,
    bf16* __restrict__ chist_t, const bf16* __restrict__ zb, int mode0)
{
    __shared__ __align__(16) uint8_t smem[65536];
    bf16* sA = (bf16*)smem;                       // [2][64*128]
    bf16* sB = (bf16*)(smem + 32768);             // [2][64*128]
    float (*gld)[68] = (float(*)[68])smem;        // overlaid post-loop (17.4KB)

    const int tid = threadIdx.x, lane = tid & 63, w = tid >> 6;
    const int wr = w >> 1, wc = w & 1;
    const int m0 = blockIdx.x * 64, n0 = blockIdx.y * 64;

    // staging geometry: chunkslot = q*256+tid -> row r=q*16+(tid>>4), chunk kq=tid&15
    const int kq = tid & 15, rr = tid >> 4;
    const int swz = ((kq ^ rr) << 3);             // source elem offset (involution)
    int abS[4], ay[4], ax[4]; bool rok[4];
#pragma unroll
    for (int q = 0; q < 4; ++q) {
        int ra = m0 + q * 16 + rr;
        rok[q] = ra < M_;
        int b = ra / S_, s = ra - b * S_;
        abS[q] = b * S_;
        ay[q] = s / HW_; ax[q] = s - ay[q] * HW_;
    }

    const int NS = mode0 ? 18 : 9;

    f32x4 accX[2][2], accH[2][2];
    if (mode0) {
#pragma unroll
        for (int fn = 0; fn < 2; ++fn) {
            int np = n0 + wc * 32 + fn * 16 + (lane & 15);
            float bv = bconv[((np & 3) << 7) + (np >> 2)];
            f32x4 b4 = {bv, bv, bv, bv};
            accX[0][fn] = b4; accX[1][fn] = b4;
            f32x4 z4 = {0.f, 0.f, 0.f, 0.f};
            accH[0][fn] = z4; accH[1][fn] = z4;
        }
    } else {
#pragma unroll
        for (int fm = 0; fm < 2; ++fm) {
            int row = m0 + wr * 32 + fm * 16 + ((lane >> 4) << 2);
#pragma unroll
            for (int fn = 0; fn < 2; ++fn) {
                int col = n0 + wc * 32 + fn * 16 + (lane & 15);
#pragma unroll
                for (int j = 0; j < 4; ++j)
                    accH[fm][fn][j] = Gx[(size_t)(row + j) * N_ + col];
            }
        }
    }

    auto stage = [&](int st, int dbuf) {
        int xph = (mode0 && st < 9);
        int kid = xph ? st : (mode0 ? st - 9 : st);
        int ky = kid / 3, kx = kid - ky * 3;
        const bf16* Asrc = xph ? xTt : hT;
        const bf16* Wsrc = xph ? WxP : WhP;
        bf16* lA = sA + dbuf * 8192;
        bf16* lB = sB + dbuf * 8192;
#pragma unroll
        for (int q = 0; q < 4; ++q) {
            int y2 = ay[q] + ky - 1, x2 = ax[q] + kx - 1;
            const bf16* rb = (rok[q] && (unsigned)y2 < (unsigned)HW_ && (unsigned)x2 < (unsigned)HW_)
                ? Asrc + (((size_t)(abS[q] + y2 * HW_ + x2)) << 7) : zb;
            gl16(rb + swz, lA + q * 2048 + w * 512);
            gl16(Wsrc + (size_t)(n0 + q * 16 + rr) * KH_ + kid * 128 + swz, lB + q * 2048 + w * 512);
        }
    };

    auto compute = [&](int dbuf, f32x4 (&acc)[2][2]) {
        const bf16* lA = sA + dbuf * 8192;
        const bf16* lB = sB + dbuf * 8192;
        short8 af[2][4], bq[2][4];
#pragma unroll
        for (int kh = 0; kh < 4; ++kh) {
            int c = kh * 4 + (lane >> 4);
            int xr = (c ^ (lane & 15)) << 3;
#pragma unroll
            for (int fm = 0; fm < 2; ++fm) {
                int r = wr * 32 + fm * 16 + (lane & 15);
                af[fm][kh] = *(const short8*)(lA + r * 128 + xr);
            }
#pragma unroll
            for (int fn = 0; fn < 2; ++fn) {
                int r = wc * 32 + fn * 16 + (lane & 15);
                bq[fn][kh] = *(const short8*)(lB + r * 128 + xr);
            }
        }
#pragma unroll
        for (int kh = 0; kh < 4; ++kh)
#pragma unroll
            for (int fm = 0; fm < 2; ++fm)
#pragma unroll
                for (int fn = 0; fn < 2; ++fn)
                    acc[fm][fn] = __builtin_amdgcn_mfma_f32_16x16x32_bf16(
                        af[fm][kh], bq[fn][kh], acc[fm][fn], 0, 0, 0);
    };

    stage(0, 0);
    __syncthreads();
#pragma unroll 1
    for (int st = 0; st < NS; ++st) {
        if (st + 1 < NS) stage(st + 1, (st + 1) & 1);
        if (mode0 && st < 9) compute(st & 1, accX);
        else                 compute(st & 1, accH);
        __syncthreads();
    }

    if (mode0) {
#pragma unroll
        for (int fm = 0; fm < 2; ++fm) {
            int row = m0 + wr * 32 + fm * 16 + ((lane >> 4) << 2);
#pragma unroll
            for (int fn = 0; fn < 2; ++fn) {
                int col = n0 + wc * 32 + fn * 16 + (lane & 15);
#pragma unroll
                for (int j = 0; j < 4; ++j) {
                    Gx[(size_t)(row + j) * N_ + col] = accX[fm][fn][j];
                    accH[fm][fn][j] += accX[fm][fn][j];
                }
            }
        }
    }

    // acc -> LDS (aliases sA; all LDS reads drained by final loop barrier)
#pragma unroll
    for (int fm = 0; fm < 2; ++fm)
#pragma unroll
        for (int fn = 0; fn < 2; ++fn) {
            int row = wr * 32 + fm * 16 + ((lane >> 4) << 2);
            int col = wc * 32 + fn * 16 + (lane & 15);
#pragma unroll
            for (int j = 0; j < 4; ++j) gld[row + j][col] = accH[fm][fn][j];
        }
    __syncthreads();

#pragma unroll
    for (int q2 = 0; q2 < 4; ++q2) {
        int e = tid + q2 * 256;                   // 1024 = 64 rows x 16 channels
        int row = e >> 4, cc = e & 15;
        int m = m0 + row;
        if (m >= M_) continue;
        int b = m / S_, s = m - b * S_;
        int cg = (n0 >> 2) + cc;
        float g0 = gld[row][cc * 4 + 0], g1 = gld[row][cc * 4 + 1];
        float g2 = gld[row][cc * 4 + 2], g3 = gld[row][cc * 4 + 3];
        float ig = sigm_f(g0);
        float fg = sigm_f(g1);
        float og = sigm_f(g2);
        float gg = tanh_f(g3);
        size_t ci = (((size_t)b * S_ + s) << 7) + cg;
        float co = cbuf[ci];
        if (mask_c) co *= mask_c[b];
        float cn = fg * co + ig * gg;
        cbuf[ci] = cn;
        float hn = og * tanh_f(cn);
        float am = mask_a ? mask_a[b] : 1.f;
        hTN[ci] = __float2bfloat16(hn * am);
        if (chist_t) chist_t[(size_t)b * KL_ + s * C_ + cg] = __float2bfloat16(cn);
    }
}

// ---------------------------------------------------------------------------
// Deferred linear: out = relu(chist @ Wlp^T + blin). 64x64 tile, BK=128.
// ---------------------------------------------------------------------------
__global__ __launch_bounds__(256, 2) void k_lingemm(
    const bf16* __restrict__ Ac, const bf16* __restrict__ Wl,
    const float* __restrict__ blin, float* __restrict__ out)
{
    __shared__ __align__(16) uint8_t smem[65536];
    bf16* sA = (bf16*)smem;
    bf16* sB = (bf16*)(smem + 32768);

    const int tid = threadIdx.x, lane = tid & 63, w = tid >> 6;
    const int wr = w >> 1, wc = w & 1;
    const int m0 = blockIdx.x * 64, n0 = blockIdx.y * 64;
    const int kq = tid & 15, rr = tid >> 4;
    const int swz = ((kq ^ rr) << 3);

    f32x4 acc[2][2];
#pragma unroll
    for (int fn = 0; fn < 2; ++fn) {
        int np = n0 + wc * 32 + fn * 16 + (lane & 15);
        float bv = blin[np];
        f32x4 b4 = {bv, bv, bv, bv};
        acc[0][fn] = b4; acc[1][fn] = b4;
    }

    auto stage = [&](int st, int dbuf) {
        bf16* lA = sA + dbuf * 8192;
        bf16* lB = sB + dbuf * 8192;
#pragma unroll
        for (int q = 0; q < 4; ++q) {
            gl16(Ac + (size_t)(m0 + q * 16 + rr) * KL_ + st * 128 + swz, lA + q * 2048 + w * 512);
            gl16(Wl + (size_t)(n0 + q * 16 + rr) * KL_ + st * 128 + swz, lB + q * 2048 + w * 512);
        }
    };
    auto compute = [&](int dbuf) {
        const bf16* lA = sA + dbuf * 8192;
        const bf16* lB = sB + dbuf * 8192;
        short8 af[2][4], bq[2][4];
#pragma unroll
        for (int kh = 0; kh < 4; ++kh) {
            int c = kh * 4 + (lane >> 4);
            int xr = (c ^ (lane & 15)) << 3;
#pragma unroll
            for (int fm = 0; fm < 2; ++fm) {
                int r = wr * 32 + fm * 16 + (lane & 15);
                af[fm][kh] = *(const short8*)(lA + r * 128 + xr);
            }
#pragma unroll
            for (int fn = 0; fn < 2; ++fn) {
                int r = wc * 32 + fn * 16 + (lane & 15);
                bq[fn][kh] = *(const short8*)(lB + r * 128 + xr);
            }
        }
#pragma unroll
        for (int kh = 0; kh < 4; ++kh)
#pragma unroll
            for (int fm = 0; fm < 2; ++fm)
#pragma unroll
                for (int fn = 0; fn < 2; ++fn)
                    acc[fm][fn] = __builtin_amdgcn_mfma_f32_16x16x32_bf16(
                        af[fm][kh], bq[fn][kh], acc[fm][fn], 0, 0, 0);
    };

    stage(0, 0);
    __syncthreads();
#pragma unroll 1
    for (int st = 0; st < 49; ++st) {
        if (st + 1 < 49) stage(st + 1, (st + 1) & 1);
        compute(st & 1);
        __syncthreads();
    }

#pragma unroll
    for (int fm = 0; fm < 2; ++fm)
#pragma unroll
        for (int fn = 0; fn < 2; ++fn) {
            int col = n0 + wc * 32 + fn * 16 + (lane & 15);
            int rb  = m0 + wr * 32 + fm * 16 + ((lane >> 4) << 2);
#pragma unroll
            for (int j = 0; j < 4; ++j)
                out[(size_t)(rb + j) * N_ + col] = fmaxf(acc[fm][fn][j], 0.f);
        }
}

// ---------------------------------------------------------------------------
// Weight prep: split Wconv into Wx/Wh, n' = 4c+gate rows, k = kid*128+ic
// ---------------------------------------------------------------------------
__global__ __launch_bounds__(256) void k_wsplit(const float* __restrict__ Wc,
                                               bf16* __restrict__ WxP, bf16* __restrict__ WhP) {
    int idx = blockIdx.x * 256 + threadIdx.x;     // 512*288
    if (idx >= 512 * 288) return;
    int np = idx / 288, kq = idx % 288;
    int oc = ((np & 3) << 7) + (np >> 2);
    int kk = kq * 8;
    int half = kk >= KH_;
    int krel = kk - half * KH_;
    short8 v;
#pragma unroll
    for (int j = 0; j < 8; ++j) {
        int kr = krel + j;
        int kid = kr >> 7, ic = (kr & 127) + half * 128;
        bfbits bb; bb.b = __float2bfloat16(Wc[((size_t)oc * 256 + ic) * 9 + kid]);
        v[j] = bb.s;
    }
    bf16* dst = half ? WhP : WxP;
    *reinterpret_cast<short8*>(dst + (size_t)np * KH_ + krel) = v;
}

// Wlin reorder: k' = s*128+c
__global__ __launch_bounds__(256) void k_wlin2(const float* __restrict__ Wl, bf16* __restrict__ Wp) {
    int idx = blockIdx.x * 256 + threadIdx.x;     // 512*784
    if (idx >= 512 * 784) return;
    int np = idx / 784, kq = idx % 784;
    short8 v;
#pragma unroll
    for (int j = 0; j < 8; ++j) {
        int kp = kq * 8 + j;
        int s = kp >> 7, c = kp & 127;
        bfbits bb; bb.b = __float2bfloat16(Wl[(size_t)np * KL_ + c * S_ + s]);
        v[j] = bb.s;
    }
    *reinterpret_cast<short8*>(Wp + (size_t)np * KL_ + kq * 8) = v;
}

// x (T*B, C, 49) f32 -> xT (T*B, 49, 128) bf16
__global__ __launch_bounds__(256) void k_xpose(const float* __restrict__ x, bf16* __restrict__ xT) {
    int idx = blockIdx.x * 256 + threadIdx.x;     // 1024*784
    if (idx >= 1024 * 784) return;
    int r = idx / 784;
    int rem = idx % 784;
    int s = rem / 16, c8 = (rem & 15) * 8;
    const float* sp = x + (size_t)r * CS_ + c8 * S_ + s;
    short8 v;
#pragma unroll
    for (int j = 0; j < 8; ++j) { bfbits bb; bb.b = __float2bfloat16(sp[j * S_]); v[j] = bb.s; }
    *reinterpret_cast<short8*>(xT + (((size_t)r * S_ + s) << 7) + c8) = v;
}

// h0*mask0 -> hT bf16 (b,s,c);  c0 -> cbuf f32 (b,s,c)
__global__ __launch_bounds__(256) void k_hcprep(const float* __restrict__ hxs,
                                                const float* __restrict__ mask0,
                                                bf16* __restrict__ hT, float* __restrict__ cbuf) {
    int idx = blockIdx.x * 256 + threadIdx.x;     // 32*784
    if (idx >= 32 * 784) return;
    int b = idx / 784;
    int rem = idx % 784;
    int s = rem / 16, c8 = (rem & 15) * 8;
    float m = mask0[b];
    const float* hp = hxs + (size_t)b * ICS_ + c8 * S_ + s;
    const float* cp = hp + CS_;
    size_t o = (((size_t)b * S_ + s) << 7) + c8;
    short8 v;
#pragma unroll
    for (int j = 0; j < 8; ++j) {
        bfbits bb; bb.b = __float2bfloat16(hp[j * S_] * m); v[j] = bb.s;
        cbuf[o + j] = cp[j * S_];
    }
    *reinterpret_cast<short8*>(hT + o) = v;
}

__global__ __launch_bounds__(256) void k_zero16(uint4* __restrict__ p, int n) {
    int i = blockIdx.x * 256 + threadIdx.x;
    if (i < n) p[i] = make_uint4(0, 0, 0, 0);
}

// final state: out[b][ch][s], ch<128 from hT bf16, else cbuf f32 (both (b,s,c))
__global__ __launch_bounds__(256) void k_final(const bf16* __restrict__ hT, const float* __restrict__ cbuf,
                                               float* __restrict__ out) {
    int i = blockIdx.x * 256 + threadIdx.x;       // 32*12544
    if (i >= B_ * ICS_) return;
    int b = i / ICS_, r = i % ICS_;
    int ch = r / S_, s = r % S_;
    size_t o = (((size_t)b * S_ + s) << 7);
    out[i] = (ch < C_) ? __bfloat162float(hT[o + ch]) : cbuf[o + (ch - C_)];
}

extern "C" void kernel_launch(void* const* d_in, const int* in_sizes, int n_in,
                              void* d_out, int out_size, void* d_ws, size_t ws_size,
                              hipStream_t stream) {
    (void)in_sizes; (void)n_in; (void)out_size; (void)ws_size;
    const float* x     = (const float*)d_in[0];
    const float* hxs   = (const float*)d_in[1];
    const float* masks = (const float*)d_in[2];
    const float* Wconv = (const float*)d_in[3];
    const float* bconv = (const float*)d_in[4];
    const float* Wlin  = (const float*)d_in[5];
    const float* blin  = (const float*)d_in[6];
    float* out = (float*)d_out;

    uint8_t* p = (uint8_t*)d_ws;
    bf16* WxP   = (bf16*)p;   p += (size_t)512 * KH_ * 2;        // 1.18 MB
    bf16* WhP   = (bf16*)p;   p += (size_t)512 * KH_ * 2;        // 1.18 MB
    bf16* Wlp   = (bf16*)p;   p += (size_t)512 * KL_ * 2;        // 6.42 MB
    bf16* xT    = (bf16*)p;   p += (size_t)1024 * S_ * C_ * 2;   // 12.85 MB
    bf16* hA    = (bf16*)p;   p += (size_t)B_ * S_ * C_ * 2;     // 0.40 MB
    bf16* hB    = (bf16*)p;   p += (size_t)B_ * S_ * C_ * 2;     // 0.40 MB
    float* cbuf = (float*)p;  p += (size_t)B_ * S_ * C_ * 4;     // 0.80 MB
    float* Gx   = (float*)p;  p += (size_t)MR_ * N_ * 4;         // 3.28 MB
    bf16* chist = (bf16*)p;   p += (size_t)1024 * KL_ * 2;       // 12.85 MB
    bf16* zb    = (bf16*)p;   p += 1024;                         // zero page
    bf16* hbufs[2] = {hA, hB};

    k_wsplit<<<576, 256, 0, stream>>>(Wconv, WxP, WhP);
    k_wlin2<<<1568, 256, 0, stream>>>(Wlin, Wlp);
    k_xpose<<<3136, 256, 0, stream>>>(x, xT);
    k_hcprep<<<98, 256, 0, stream>>>(hxs, masks, hA, cbuf);
    k_zero16<<<1, 256, 0, stream>>>((uint4*)zb, 64);

    int g = 0;
    for (int t = 0; t < T_; ++t) {
        const bf16* xTt = xT + (size_t)t * B_ * S_ * C_;
        for (int rd = 0; rd < 3; ++rd) {
            const float* mc = (rd == 0) ? masks + (size_t)t * B_ : nullptr;
            const float* ma = (rd == 2 && t < T_ - 1) ? masks + (size_t)(t + 1) * B_ : nullptr;
            bf16* ct = (rd == 2) ? chist + (size_t)t * B_ * KL_ : nullptr;
            k_fgemm<<<dim3(25, 8), 256, 0, stream>>>(
                (rd == 0) ? xTt : nullptr, hbufs[g & 1], hbufs[(g + 1) & 1],
                WxP, WhP, bconv, Gx, cbuf, mc, ma, ct, zb, (rd == 0) ? 1 : 0);
            ++g;
        }
    }

    k_lingemm<<<dim3(16, 8), 256, 0, stream>>>(chist, Wlp, blin, out);
    k_final<<<1568, 256, 0, stream>>>(hbufs[0], cbuf, out + (size_t)T_ * B_ * HS_);
}